// Round 1
// baseline (120.741 us; speedup 1.0000x reference)
//
#include <hip/hip_runtime.h>
#include <hip/hip_bf16.h>

#define B_ 8192
#define D_ 256
#define EPS_ 1e-6f
#define MARGIN_ 1.0f
#define TILES_ (B_ / 128)              // 64
#define NBLK_ (TILES_ * (TILES_ + 1) / 2)  // 2080

typedef float floatx4 __attribute__((ext_vector_type(4)));
typedef __bf16 bf16x4 __attribute__((ext_vector_type(4)));
typedef __bf16 bf16x8 __attribute__((ext_vector_type(8)));

// ws layout:
//   [0, B*D*2)                : x cast to bf16 (row-major)
//   [XQ, XQ+B*4)              : p[i] = ||x_i||^2 + 2*eps*sum(x_i)
//   [XQ+B*4, XQ+2*B*4)        : q[j] = ||x_j||^2 - 2*eps*sum(x_j)
//   [XQ+2*B*4, +4)            : float accumulator
#define XBF_BYTES (B_ * D_ * 2)

// ---------------- prep: p/q + bf16 cast, one wave per row ----------------
__global__ void prep_kernel(const float* __restrict__ x, __bf16* __restrict__ xbf,
                            float* __restrict__ p, float* __restrict__ q,
                            float* __restrict__ acc) {
    const int wave = threadIdx.x >> 6;   // 4 waves/block, 1 row/wave
    const int lane = threadIdx.x & 63;
    const int row  = blockIdx.x * 4 + wave;

    const float4 v = *(const float4*)(x + row * D_ + lane * 4);
    float sq = v.x * v.x + v.y * v.y + v.z * v.z + v.w * v.w;
    float rs = v.x + v.y + v.z + v.w;
    #pragma unroll
    for (int off = 32; off > 0; off >>= 1) {
        sq += __shfl_down(sq, off);
        rs += __shfl_down(rs, off);
    }
    if (lane == 0) {
        p[row] = sq + 2.0f * EPS_ * rs;
        q[row] = sq - 2.0f * EPS_ * rs;
    }
    bf16x4 h = { (__bf16)v.x, (__bf16)v.y, (__bf16)v.z, (__bf16)v.w };
    *(bf16x4*)(xbf + row * D_ + lane * 4) = h;

    if (blockIdx.x == 0 && threadIdx.x == 0) *acc = 0.0f;
}

// ---------------- tile: 128x128 gram tile + fused loss epilogue ----------------
__global__ __launch_bounds__(256, 2)
void tile_kernel(const unsigned short* __restrict__ xbf,
                 const float* __restrict__ p, const float* __restrict__ q,
                 const int* __restrict__ label, float* __restrict__ acc) {
    // decode triangular tile index (ti <= tj)
    int b = blockIdx.x;
    int ti = 0, rem = TILES_;
    while (b >= rem) { b -= rem; ++ti; --rem; }
    const int tj = ti + b;
    const int i0 = ti * 128, j0 = tj * 128;
    const bool diag = (ti == tj);

    __shared__ __align__(16) unsigned short As[128 * 72];  // BK=64, pad 8
    __shared__ __align__(16) unsigned short Bs[128 * 72];
    __shared__ float pi_s[128], qj_s[128];
    __shared__ int li_s[128], lj_s[128];
    __shared__ float wsum[4];

    const int tid = threadIdx.x;
    if (tid < 128) {
        pi_s[tid] = p[i0 + tid];
        li_s[tid] = label[i0 + tid];
    } else {
        const int t = tid - 128;
        qj_s[t] = q[j0 + t];
        lj_s[t] = label[j0 + t];
    }

    const int wave = tid >> 6, lane = tid & 63;
    const int quad = lane >> 4, r = lane & 15;
    const int wm = wave >> 1, wn = wave & 1;   // 2x2 wave grid, 64x64 each

    floatx4 accv[16];
    #pragma unroll
    for (int t = 0; t < 16; ++t) accv[t] = (floatx4)0.0f;

    const int srow = tid >> 3;           // 0..31
    const int scol = (tid & 7) * 8;      // 0..56 step 8

    for (int k0 = 0; k0 < D_; k0 += 64) {
        __syncthreads();  // prior-iter LDS reads done (also covers pi_s staging)
        #pragma unroll
        for (int pass = 0; pass < 4; ++pass) {
            const int rr = pass * 32 + srow;
            const uint4 av = *(const uint4*)(xbf + (size_t)(i0 + rr) * D_ + k0 + scol);
            *(uint4*)(&As[rr * 72 + scol]) = av;
            const uint4 bv = *(const uint4*)(xbf + (size_t)(j0 + rr) * D_ + k0 + scol);
            *(uint4*)(&Bs[rr * 72 + scol]) = bv;
        }
        __syncthreads();
        #pragma unroll
        for (int k2 = 0; k2 < 64; k2 += 32) {
            bf16x8 af[4], bfr[4];
            #pragma unroll
            for (int mt = 0; mt < 4; ++mt)
                af[mt] = *(const bf16x8*)(&As[(wm * 64 + mt * 16 + r) * 72 + k2 + quad * 8]);
            #pragma unroll
            for (int nt = 0; nt < 4; ++nt)
                bfr[nt] = *(const bf16x8*)(&Bs[(wn * 64 + nt * 16 + r) * 72 + k2 + quad * 8]);
            #pragma unroll
            for (int mt = 0; mt < 4; ++mt)
                #pragma unroll
                for (int nt = 0; nt < 4; ++nt)
                    accv[mt * 4 + nt] = __builtin_amdgcn_mfma_f32_16x16x32_bf16(
                        af[mt], bfr[nt], accv[mt * 4 + nt], 0, 0, 0);
        }
    }

    // epilogue: C/D layout col=lane&15, row=quad*4+reg (m89/m91-verified)
    float sum = 0.0f;
    const float Deps2 = (float)D_ * EPS_ * EPS_;
    #pragma unroll
    for (int mt = 0; mt < 4; ++mt) {
        #pragma unroll
        for (int nt = 0; nt < 4; ++nt) {
            const floatx4 a = accv[mt * 4 + nt];
            #pragma unroll
            for (int reg = 0; reg < 4; ++reg) {
                const int il = wm * 64 + mt * 16 + quad * 4 + reg;
                const int jl = wn * 64 + nt * 16 + r;
                float sq = pi_s[il] + qj_s[jl] - 2.0f * a[reg] + Deps2;
                sq = fmaxf(sq, 1e-12f);
                const float dist = sqrtf(sq);
                const float hm = fmaxf(MARGIN_ - dist, 0.0f);
                float v = (li_s[il] == lj_s[jl]) ? sq : hm * hm;
                if (diag && il >= jl) v = 0.0f;  // strict upper triangle only
                sum += v;
            }
        }
    }
    #pragma unroll
    for (int off = 32; off > 0; off >>= 1) sum += __shfl_down(sum, off);
    if (lane == 0) wsum[wave] = sum;
    __syncthreads();
    if (tid == 0) atomicAdd(acc, wsum[0] + wsum[1] + wsum[2] + wsum[3]);
}

// ---------------- finalize ----------------
__global__ void finalize_kernel(const float* __restrict__ acc, float* __restrict__ out) {
    const double cnt = (double)B_ * (double)(B_ - 1) / 2.0 + 1e-6;
    out[0] = (float)((double)acc[0] / cnt);
}

extern "C" void kernel_launch(void* const* d_in, const int* in_sizes, int n_in,
                              void* d_out, int out_size, void* d_ws, size_t ws_size,
                              hipStream_t stream) {
    const float* x = (const float*)d_in[0];
    const int* label = (const int*)d_in[1];
    float* out = (float*)d_out;

    char* ws = (char*)d_ws;
    __bf16* xbf = (__bf16*)ws;
    float* p = (float*)(ws + XBF_BYTES);
    float* q = (float*)(ws + XBF_BYTES + B_ * 4);
    float* acc = (float*)(ws + XBF_BYTES + 2 * B_ * 4);

    prep_kernel<<<B_ / 4, 256, 0, stream>>>(x, xbf, p, q, acc);
    tile_kernel<<<NBLK_, 256, 0, stream>>>((const unsigned short*)xbf, p, q, label, acc);
    finalize_kernel<<<1, 1, 0, stream>>>(acc, out);
}